// Round 7
// baseline (151.340 us; speedup 1.0000x reference)
//
#include <hip/hip_runtime.h>

#define IMG_W 512
#define IMG_H 512
#define BATCH 64
#define STRIP_ROWS 16
#define STRIPS_PER_IMG (IMG_H / STRIP_ROWS)        // 32
#define NSTRIPS (BATCH * STRIPS_PER_IMG)           // 2048 strips, 1 per wave
#define NB_MAIN (NSTRIPS / 4)                      // 512 blocks x 4 waves
#define NB_PROBE 256                               // probe: 1 block/CU
#define NPIX (BATCH * IMG_W * IMG_H)

typedef float f32x4 __attribute__((ext_vector_type(4)));

__device__ __forceinline__ float fast_sqrtf(float x) {
    return __builtin_amdgcn_sqrtf(x);
}

// R15: main kernel = R12 byte-identical (known-pass, 43.4us). R13+R14 both
// core-dumped and both contained the inline-asm stream_probe (R14's main was
// R12-verbatim) -> the asm probe is the prime suspect and is replaced by a
// PLAIN-HIP probe: same strip geometry (18 clamped 2KB rows/wave, f32x4
// pairs, 37MB over images 0..31), compiler-scheduled, no asm, no manual
// vmcnt. Discriminates T-A (probe ~6us: delivery fine, hand-schedule is the
// limiter -> de-asm the main kernel) vs T-B (probe ~10-13us: pattern
// delivery ceiling -> restructure addressing).

#define GLOAD(dst, ptr)                                                        \
    asm volatile("global_load_dwordx4 %0, %1, off" : "=v"(dst) : "v"(ptr))

// rolling-buffer slots (k is a compile-time row index, -1..16)
#define S6(k) (((k) + 1) % 6)
#define S3(k) (((k) + 1) % 3)

// window element j (0..9) of row k: 0 = left halo, 9 = right halo
#define WEL(A, B, HL, HR, k, j)                                                \
    ((j) == 0 ? HL[S3(k)]                                                      \
              : ((j) == 9 ? HR[S3(k)]                                          \
                          : ((j) <= 4 ? A[S6(k)][(j) - 1] : B[S6(k)][(j) - 5])))

// issue the 2 dwordx4 loads of row k (y-clamped; halo rows zeroed post-wait)
#define ISSUE(k, A, B, IMG)                                                    \
    {                                                                          \
        int gy_ = stripy + (k);                                                \
        gy_ = gy_ < 0 ? 0 : (gy_ > IMG_H - 1 ? IMG_H - 1 : gy_);               \
        const float* r_ = (IMG) + ((size_t)gy_ << 9) + x0;                     \
        GLOAD(A[S6(k)], r_);                                                   \
        GLOAD(B[S6(k)], r_ + 4);                                               \
    }

// after row k's data is present: build halo floats + horizontal 1-2-1 sums
#define PREP(k, A, B, HL, HR, HS)                                              \
    {                                                                          \
        float l_ = __shfl_up(B[S6(k)][3], 1, 64);                              \
        float r_ = __shfl_down(A[S6(k)][0], 1, 64);                            \
        HL[S3(k)] = (lane == 0) ? 0.f : l_;                                    \
        HR[S3(k)] = (lane == 63) ? 0.f : r_;                                   \
        _Pragma("unroll")                                                      \
        for (int j = 0; j < 8; ++j)                                            \
            HS[S3(k)][j] = fmaf(2.f, WEL(A, B, HL, HR, k, j + 1),              \
                                WEL(A, B, HL, HR, k, j)) +                     \
                           WEL(A, B, HL, HR, k, j + 2);                        \
    }

// output row r of image p: store magnitudes into magrow
#define OUT_P(r)                                                               \
    {                                                                          \
        float c9_[10];                                                         \
        _Pragma("unroll")                                                      \
        for (int j = 0; j < 10; ++j)                                           \
            c9_[j] = fmaf(2.f, WEL(pA, pB, hlP, hrP, (r), j),                  \
                          WEL(pA, pB, hlP, hrP, (r)-1, j)) +                   \
                     WEL(pA, pB, hlP, hrP, (r) + 1, j);                        \
        _Pragma("unroll")                                                      \
        for (int j = 0; j < 8; ++j) {                                          \
            float gh = hsP[S3((r) + 1)][j] - hsP[S3((r)-1)][j];                \
            float gv = c9_[j + 2] - c9_[j];                                    \
            magrow[j] = fast_sqrtf(fmaf(gv, gv, fmaf(gh, gh, 1e-18f)));        \
        }                                                                      \
    }

// output row r of image t: fused |magt - magp| accumulation
#define OUT_T(r)                                                               \
    {                                                                          \
        float c9_[10];                                                         \
        _Pragma("unroll")                                                      \
        for (int j = 0; j < 10; ++j)                                           \
            c9_[j] = fmaf(2.f, WEL(tA, tB, hlT, hrT, (r), j),                  \
                          WEL(tA, tB, hlT, hrT, (r)-1, j)) +                   \
                     WEL(tA, tB, hlT, hrT, (r) + 1, j);                        \
        _Pragma("unroll")                                                      \
        for (int j = 0; j < 8; ++j) {                                          \
            float gh = hsT[S3((r) + 1)][j] - hsT[S3((r)-1)][j];                \
            float gv = c9_[j + 2] - c9_[j];                                    \
            float mt = fast_sqrtf(fmaf(gv, gv, fmaf(gh, gh, 1e-18f)));         \
            lsum += fabsf(mt - magrow[j]); /* == sqrt(d^2+eps)*(d^2!=0) */     \
        }                                                                      \
    }

// One output row (R12 schedule). Issue order: ...P_{r+2} T_{r+2} P_{r+3}...
// wait-p at r: outstanding after P_{r+1} = T_{r+1},P_{r+2},T_{r+2} = 6 insts.
// wait-t at r: outstanding after T_{r+1} = P_{r+2},T_{r+2},P_{r+3} = 6 insts.
// Tail: r=14 -> (6,4); r=15 -> (2,0). sched_barrier after each wait: rule #18.
#define ITER(r, WP, WT)                                                        \
    {                                                                          \
        float magrow[8];                                                       \
        asm volatile("s_waitcnt vmcnt(" #WP ")" ::: "memory");                 \
        __builtin_amdgcn_sched_barrier(0);                                     \
        if ((r) == 0 && stop_) { pA[S6(-1)] = z4; pB[S6(-1)] = z4; }           \
        if ((r) == 15 && sbot_) { pA[S6(16)] = z4; pB[S6(16)] = z4; }          \
        if ((r) == 0) {                                                        \
            PREP(-1, pA, pB, hlP, hrP, hsP)                                    \
            PREP(0, pA, pB, hlP, hrP, hsP)                                     \
        }                                                                      \
        PREP((r) + 1, pA, pB, hlP, hrP, hsP)                                   \
        if ((r) <= 13) ISSUE((r) + 3, pA, pB, imgp)                            \
        OUT_P(r)                                                               \
        asm volatile("s_waitcnt vmcnt(" #WT ")" ::: "memory");                 \
        __builtin_amdgcn_sched_barrier(0);                                     \
        if ((r) == 0 && stop_) { tA[S6(-1)] = z4; tB[S6(-1)] = z4; }           \
        if ((r) == 15 && sbot_) { tA[S6(16)] = z4; tB[S6(16)] = z4; }          \
        if ((r) == 0) {                                                        \
            PREP(-1, tA, tB, hlT, hrT, hsT)                                    \
            PREP(0, tA, tB, hlT, hrT, hsT)                                     \
        }                                                                      \
        PREP((r) + 1, tA, tB, hlT, hrT, hsT)                                   \
        if ((r) <= 13) ISSUE((r) + 3, tA, tB, imgt)                            \
        OUT_T(r)                                                               \
    }

__global__ __launch_bounds__(256, 2) void sobel_loss_kernel(
    const float* __restrict__ yp, const float* __restrict__ yt,
    float* __restrict__ bsums)
{
    __shared__ float wred[4];

    const int tid  = threadIdx.x;
    const int lane = tid & 63;
    const int w    = tid >> 6;                  // wave id 0..3

    const int bid   = blockIdx.x;
    const int b     = bid >> 3;                 // image (8 blocks/image)
    const int strip = ((bid & 7) << 2) + w;     // strip 0..31 (16 rows each)
    const int stripy = strip << 4;              // first output row
    const int x0    = lane << 3;                // cols x0..x0+7

    const bool stop_ = (strip == 0);
    const bool sbot_ = (strip == STRIPS_PER_IMG - 1);

    const float* imgp = yp + ((size_t)b << 18);
    const float* imgt = yt + ((size_t)b << 18);

    // rolling register state: row k -> slot S6(k); halo/HS -> slot S3(k)
    f32x4 pA[6], pB[6], tA[6], tB[6];
    float hlP[3], hrP[3], hlT[3], hrT[3];
    float hsP[3][8], hsT[3][8];

    const f32x4 z4 = {0.f, 0.f, 0.f, 0.f};
    float lsum = 0.f;

    // ---- prologue: rows -1..2, both images, interleaved p,t ----
    ISSUE(-1, pA, pB, imgp) ISSUE(-1, tA, tB, imgt)
    ISSUE(0,  pA, pB, imgp) ISSUE(0,  tA, tB, imgt)
    ISSUE(1,  pA, pB, imgp) ISSUE(1,  tA, tB, imgt)
    ISSUE(2,  pA, pB, imgp) ISSUE(2,  tA, tB, imgt)

    // ---- 16 output rows, constant counted waits (vmcnt 6/6), tail 6/4, 2/0
    ITER(0, 6, 6)  ITER(1, 6, 6)  ITER(2, 6, 6)  ITER(3, 6, 6)
    ITER(4, 6, 6)  ITER(5, 6, 6)  ITER(6, 6, 6)  ITER(7, 6, 6)
    ITER(8, 6, 6)  ITER(9, 6, 6)  ITER(10, 6, 6) ITER(11, 6, 6)
    ITER(12, 6, 6) ITER(13, 6, 6) ITER(14, 6, 4) ITER(15, 2, 0)

    // ---- Block reduction ----
#pragma unroll
    for (int off = 32; off > 0; off >>= 1)
        lsum += __shfl_down(lsum, off, 64);
    if (lane == 0) wred[w] = lsum;
    __syncthreads();
    if (tid == 0)
        bsums[bid] = wred[0] + wred[1] + wred[2] + wred[3];
}

// ---- PLAIN-HIP loads-only probe: same strip access shape, no inline asm.
// 256 blocks x 4 waves = 1024 strips over images 0..31 of y_p (37 MB).
// All 8 floats of each row-pair summed so the two dwordx4 loads stay whole.
// Output unused by reduce_final; cannot affect correctness.
__global__ __launch_bounds__(256) void stream_probe(
    const float* __restrict__ yp, float* __restrict__ psums)
{
    __shared__ float wred[4];
    const int tid  = threadIdx.x;
    const int lane = tid & 63;
    const int w    = tid >> 6;

    const int strip  = (blockIdx.x << 2) + w;   // 0..1023
    const int pb     = strip >> 5;              // image 0..31
    const int stripy = (strip & 31) << 4;
    const int x0     = lane << 3;

    const float* img = yp + ((size_t)pb << 18);

    float lsum = 0.f;
#pragma unroll
    for (int k = -1; k < 17; ++k) {
        int gy = stripy + k;
        gy = gy < 0 ? 0 : (gy > IMG_H - 1 ? IMG_H - 1 : gy);
        const f32x4* r = (const f32x4*)(img + ((size_t)gy << 9) + x0);
        f32x4 a = r[0];
        f32x4 bq = r[1];
        lsum += (a[0] + a[1]) + (a[2] + a[3]) + (bq[0] + bq[1]) + (bq[2] + bq[3]);
    }

#pragma unroll
    for (int off = 32; off > 0; off >>= 1)
        lsum += __shfl_down(lsum, off, 64);
    if (lane == 0) wred[w] = lsum;
    __syncthreads();
    if (tid == 0)
        psums[blockIdx.x] = wred[0] + wred[1] + wred[2] + wred[3];
}

__global__ __launch_bounds__(256) void reduce_final(
    const float* __restrict__ bsums, float* __restrict__ out)
{
    __shared__ float wred[4];
    const int tid = threadIdx.x;
    float s = 0.f;
    for (int i = tid; i < NB_MAIN; i += 256) s += bsums[i];
#pragma unroll
    for (int off = 32; off > 0; off >>= 1)
        s += __shfl_down(s, off, 64);
    if ((tid & 63) == 0) wred[tid >> 6] = s;
    __syncthreads();
    if (tid == 0)
        out[0] = (wred[0] + wred[1] + wred[2] + wred[3]) * (1.0f / (float)NPIX);
}

extern "C" void kernel_launch(void* const* d_in, const int* in_sizes, int n_in,
                              void* d_out, int out_size, void* d_ws, size_t ws_size,
                              hipStream_t stream) {
    const float* yp = (const float*)d_in[0];
    const float* yt = (const float*)d_in[1];
    float* out = (float*)d_out;

    float* bsums = (float*)d_ws;                 // 512 floats
    float* psums = (float*)d_ws + 512;           // 256 floats (probe, unused)
    sobel_loss_kernel<<<NB_MAIN, 256, 0, stream>>>(yp, yt, bsums);
    stream_probe<<<NB_PROBE, 256, 0, stream>>>(yp, psums);
    reduce_final<<<1, 256, 0, stream>>>(bsums, out);
}